// Round 3
// baseline (814.067 us; speedup 1.0000x reference)
//
#include <hip/hip_runtime.h>
#include <stdint.h>
#include <stddef.h>

// IEEE-exact ops, no FMA contraction: must reproduce the reference's f32
// arithmetic (binary labels => exact label match, absmax 0).
#pragma clang fp contract(off)

#define HW_ 262144             // H*W (512*512)
#define FEAT_BSTRIDE (256*HW_) // feature batch stride (C=256)
#define NBLK 512

__device__ __forceinline__ float quantf(float f, float mn, float denom) {
  float v = (f - mn) / denom * 255.0f;
  v = floorf(v);
  return fminf(fmaxf(v, 0.0f), 255.0f);
}
// trimap geometry: bh=bw=51, center rows/cols [230,281)
__device__ __forceinline__ bool is_center(int y, int x) {
  return (y >= 230) & (y < 281) & (x >= 230) & (x < 281);
}
__device__ __forceinline__ bool is_border(int y, int x) {
  return (y < 51) | (y >= 461) | (x < 51) | (x >= 461);
}
// wave-wide exact reductions (64-lane butterfly)
__device__ __forceinline__ int wsum(int v) {
#pragma unroll
  for (int m = 32; m >= 1; m >>= 1) v += __shfl_xor(v, m);
  return v;
}
__device__ __forceinline__ float wminf(float v) {
#pragma unroll
  for (int m = 32; m >= 1; m >>= 1) v = fminf(v, __shfl_xor(v, m));
  return v;
}
__device__ __forceinline__ float wmaxf(float v) {
#pragma unroll
  for (int m = 32; m >= 1; m >>= 1) v = fmaxf(v, __shfl_xor(v, m));
  return v;
}

// Device-wide barrier, leader-based. Safe because co-residency is guaranteed:
// __launch_bounds__(256,2) => VGPR<=128 => >=2 blocks/CU => capacity >= 512
// = grid size, so every block is resident before any spins.
// Relaxed atomics + explicit agent-scope fences (one writeback before signal,
// one invalidate after exit) — no per-poll cache invalidation.
__device__ __forceinline__ void gbar(unsigned* cnt, int idx) {
  __syncthreads();
  if (threadIdx.x == 0) {
    __threadfence();  // release: block's writes visible at device scope
    __hip_atomic_fetch_add(&cnt[idx], 1u, __ATOMIC_RELAXED,
                           __HIP_MEMORY_SCOPE_AGENT);
    while (__hip_atomic_load(&cnt[idx], __ATOMIC_RELAXED,
                             __HIP_MEMORY_SCOPE_AGENT) < NBLK)
      __builtin_amdgcn_s_sleep(1);
    __threadfence();  // acquire: invalidate stale L1/L2 before post-bar reads
  }
  __syncthreads();
}

// One kernel, 512 blocks x 256 thr; block owns 2 rows of one batch, thread
// owns 4 consecutive px for the WHOLE kernel. Features are read once and the
// quantized RGB lives in 4 VGPRs across all 5 ICM iterations (no packed
// buffer). Alpha ping-pongs through global; 6 in-kernel device barriers
// replace 6 dispatch boundaries.
__global__ __launch_bounds__(256, 2) void k_grabcut(
    const float* __restrict__ feat, const int* __restrict__ mask,
    float* __restrict__ out,
    uint8_t* __restrict__ aA, uint8_t* __restrict__ aB,
    float2* __restrict__ mm, int4* __restrict__ totals,
    int4* __restrict__ slots, unsigned* __restrict__ bar)
{
  const int blk = blockIdx.x, tid = threadIdx.x;
  const int b = blk >> 8;
  const int r0 = (blk & 255) * 2;      // first owned row within batch
  const int wid = tid >> 6, lane = tid & 63;

  __shared__ float sA[4], sB[4];
  __shared__ int xw[4][8];
  __shared__ uint32_t arowW[512];      // 4 rows x 128 alpha words

  // ---- phase 0: features -> regs, minmax partial, trimap codes ----
  const int pix = blk * 1024 + tid * 4;     // global pixel index
  const int pb = pix & (HW_ - 1);
  const int y = pb >> 9, xb = pb & 511;
  const float* fbp = feat + (size_t)b * FEAT_BSTRIDE;
  float4 cr = *reinterpret_cast<const float4*>(fbp + pb);
  float4 cg = *reinterpret_cast<const float4*>(fbp + HW_ + pb);
  float4 cb = *reinterpret_cast<const float4*>(fbp + 2 * HW_ + pb);
  int4 mk = *reinterpret_cast<const int4*>(mask + pix);
  float rs[4] = {cr.x, cr.y, cr.z, cr.w};
  float gs[4] = {cg.x, cg.y, cg.z, cg.w};
  float bs[4] = {cb.x, cb.y, cb.z, cb.w};
  int mks[4] = {mk.x, mk.y, mk.z, mk.w};

  float mn = fminf(fminf(fminf(rs[0], rs[1]), fminf(rs[2], rs[3])),
                   fminf(fminf(gs[0], gs[1]), fminf(gs[2], gs[3])));
  mn = fminf(mn, fminf(fminf(bs[0], bs[1]), fminf(bs[2], bs[3])));
  float mx = fmaxf(fmaxf(fmaxf(rs[0], rs[1]), fmaxf(rs[2], rs[3])),
                   fmaxf(fmaxf(gs[0], gs[1]), fmaxf(gs[2], gs[3])));
  mx = fmaxf(mx, fmaxf(fmaxf(bs[0], bs[1]), fmaxf(bs[2], bs[3])));
  mn = wminf(mn); mx = wmaxf(mx);
  if (lane == 0) { sA[wid] = mn; sB[wid] = mx; }
  __syncthreads();
  if (tid == 0)
    mm[blk] = make_float2(fminf(fminf(sA[0], sA[1]), fminf(sA[2], sA[3])),
                          fmaxf(fmaxf(sB[0], sB[1]), fmaxf(sB[2], sB[3])));

  uint32_t code = 0;  // 2b/px: 1=fixed FG, 2=fixed BG, 3=mask-FG, 0=mask-BG
#pragma unroll
  for (int i = 0; i < 4; i++) {
    int x = xb + i;
    uint32_t c2;
    if (is_center(y, x)) c2 = 1u;
    else if (is_border(y, x)) c2 = 2u;
    else c2 = (mks[i] == 1) ? 3u : 0u;
    code |= c2 << (2 * i);
  }
  gbar(bar, 0);

  // ---- phase 1: batch minmax reduce, quantize->regs, alpha init, slot0 ----
  {
    float2 v = mm[b * 256 + tid];
    float m2 = wminf(v.x), x2 = wmaxf(v.y);
    if (lane == 0) { sA[wid] = m2; sB[wid] = x2; }
  }
  __syncthreads();
  const float bmn = fminf(fminf(sA[0], sA[1]), fminf(sA[2], sA[3]));
  const float bmx = fmaxf(fmaxf(sB[0], sB[1]), fmaxf(sB[2], sB[3]));
  const float denom = (bmx - bmn) + 1e-12f;  // f32, matches reference

  uint32_t pk[4];
  {
    uint32_t aw = 0;
    int a0 = 0, a1 = 0, a2 = 0, a3 = 0, t0 = 0, t1 = 0, t2 = 0;
#pragma unroll
    for (int i = 0; i < 4; i++) {
      int r  = (int)quantf(rs[i], bmn, denom);
      int g  = (int)quantf(gs[i], bmn, denom);
      int bl = (int)quantf(bs[i], bmn, denom);
      pk[i] = (uint32_t)r | ((uint32_t)g << 8) | ((uint32_t)bl << 16);
      uint32_t c2 = (code >> (2 * i)) & 3u;
      int a = (c2 == 1u || c2 == 3u) ? 1 : 0;
      aw |= (uint32_t)a << (8 * i);
      a0 += r * a; a1 += g * a; a2 += bl * a; a3 += a;
      t0 += r; t1 += g; t2 += bl;
    }
    *reinterpret_cast<uint32_t*>(aA + pix) = aw;
    a0 = wsum(a0); a1 = wsum(a1); a2 = wsum(a2); a3 = wsum(a3);
    t0 = wsum(t0); t1 = wsum(t1); t2 = wsum(t2);
    if (lane == 0) {
      xw[wid][0] = a0; xw[wid][1] = a1; xw[wid][2] = a2; xw[wid][3] = a3;
      xw[wid][4] = t0; xw[wid][5] = t1; xw[wid][6] = t2;
    }
    __syncthreads();
    if (tid == 0) {
      slots[blk] = make_int4(xw[0][0] + xw[1][0] + xw[2][0] + xw[3][0],
                             xw[0][1] + xw[1][1] + xw[2][1] + xw[3][1],
                             xw[0][2] + xw[1][2] + xw[2][2] + xw[3][2],
                             xw[0][3] + xw[1][3] + xw[2][3] + xw[3][3]);
      totals[blk] = make_int4(xw[0][4] + xw[1][4] + xw[2][4] + xw[3][4],
                              xw[0][5] + xw[1][5] + xw[2][5] + xw[3][5],
                              xw[0][6] + xw[1][6] + xw[2][6] + xw[3][6], 0);
    }
  }
  gbar(bar, 1);

  // ---- 5 ICM iterations ----
  for (int k = 0; k < 5; k++) {
    const uint8_t* ain = (k & 1) ? aB : aA;
    uint8_t* aout = (k & 1) ? aA : aB;
    const int4* slotIn = slots + (size_t)k * NBLK;

    // stage rows r0-1 .. r0+2 (edge-clamped within batch) into LDS
    {
      int row_i = tid >> 6;
      int src_row = r0 - 1 + row_i;
      src_row = src_row < 0 ? 0 : (src_row > 511 ? 511 : src_row);
      reinterpret_cast<uint2*>(arowW)[tid] = *reinterpret_cast<const uint2*>(
          ain + (size_t)b * HW_ + src_row * 512 + (tid & 63) * 8);
    }
    // deterministic exact-int reduce of this batch's 256 partials
    int4 sv = slotIn[b * 256 + tid];
    int4 tv = totals[b * 256 + tid];
    int v0 = wsum(sv.x), v1 = wsum(sv.y), v2 = wsum(sv.z), v3 = wsum(sv.w);
    int v4 = wsum(tv.x), v5 = wsum(tv.y), v6 = wsum(tv.z);
    if (lane == 0) {
      xw[wid][0] = v0; xw[wid][1] = v1; xw[wid][2] = v2; xw[wid][3] = v3;
      xw[wid][4] = v4; xw[wid][5] = v5; xw[wid][6] = v6;
    }
    __syncthreads();  // covers arowW staging + xw partials
    int s0 = xw[0][0] + xw[1][0] + xw[2][0] + xw[3][0];
    int s1 = xw[0][1] + xw[1][1] + xw[2][1] + xw[3][1];
    int s2 = xw[0][2] + xw[1][2] + xw[2][2] + xw[3][2];
    int s3 = xw[0][3] + xw[1][3] + xw[2][3] + xw[3][3];
    int s4 = xw[0][4] + xw[1][4] + xw[2][4] + xw[3][4];
    int s5 = xw[0][5] + xw[1][5] + xw[2][5] + xw[3][5];
    int s6 = xw[0][6] + xw[1][6] + xw[2][6] + xw[3][6];
    float fden = (float)s3 + 1e-6f;
    float bden = (float)(HW_ - s3) + 1e-6f;
    float f0 = (float)s0 / fden;             // fg_mean
    float f1 = (float)s1 / fden;
    float f2 = (float)s2 / fden;
    float g0 = (float)(s4 - s0) / bden;      // bg_mean = (total-fg)/nbg
    float g1 = (float)(s5 - s1) / bden;
    float g2 = (float)(s6 - s2) / bden;

    int lr = tid >> 7, q = tid & 127, x0 = q * 4;
    uint32_t uw = arowW[lr * 128 + q];        // up row
    uint32_t cw = arowW[(lr + 1) * 128 + q];  // center row
    uint32_t dw = arowW[(lr + 2) * 128 + q];  // down row
    const uint8_t* arowB = reinterpret_cast<const uint8_t*>(arowW);
    int lfb = arowB[(lr + 1) * 512 + (x0 > 0 ? x0 - 1 : 0)];
    int rtb = arowB[(lr + 1) * 512 + (x0 + 4 < 512 ? x0 + 4 : 511)];

    int aa0 = 0, aa1 = 0, aa2 = 0, aa3 = 0;
    uint32_t awout = 0;
    float fouts[4];
#pragma unroll
    for (int i = 0; i < 4; i++) {
      uint32_t rgb = pk[i];
      int ri = (int)(rgb & 255u);
      int gi = (int)((rgb >> 8) & 255u);
      int bi = (int)((rgb >> 16) & 255u);
      float i0 = (float)ri, i1 = (float)gi, i2 = (float)bi;  // exact
      int up = (int)((uw >> (8 * i)) & 255u);
      int dn = (int)((dw >> (8 * i)) & 255u);
      int lf = (i == 0) ? lfb : (int)((cw >> (8 * (i - 1))) & 255u);
      int rt = (i == 3) ? rtb : (int)((cw >> (8 * (i + 1))) & 255u);
      float nb = (float)(((up + dn) + lf) + rt) * 0.25f;     // exact in f32
      float pair = 50.0f * ((2.0f * nb) - 1.0f);             // exact in f32
      float d0 = i0 - f0, d1 = i1 - f1, d2 = i2 - f2;
      float df = ((d0 * d0) + (d1 * d1)) + (d2 * d2);
      float u0 = i0 - g0, u1 = i1 - g1, u2 = i2 - g2;
      float db = ((u0 * u0) + (u1 * u1)) + (u2 * u2);
      float score = (db - df) + pair;
      uint32_t c2 = (code >> (2 * i)) & 3u;
      int a;
      if (c2 == 1u) a = 1;                  // fixed FG
      else if (c2 == 2u) a = 0;             // fixed BG
      else a = (score > 0.0f) ? 1 : 0;
      awout |= (uint32_t)a << (8 * i);
      fouts[i] = (float)a;
      aa0 += ri * a; aa1 += gi * a; aa2 += bi * a; aa3 += a;
    }
    *reinterpret_cast<uint32_t*>(aout + pix) = awout;
    if (k == 4) {
      *reinterpret_cast<float4*>(out + pix) =
          make_float4(fouts[0], fouts[1], fouts[2], fouts[3]);
    } else {
      aa0 = wsum(aa0); aa1 = wsum(aa1); aa2 = wsum(aa2); aa3 = wsum(aa3);
      __syncthreads();  // all reads of xw/arowW done before rewrite
      if (lane == 0) {
        xw[wid][0] = aa0; xw[wid][1] = aa1; xw[wid][2] = aa2; xw[wid][3] = aa3;
      }
      __syncthreads();
      if (tid == 0)
        slots[(size_t)(k + 1) * NBLK + blk] =
            make_int4(xw[0][0] + xw[1][0] + xw[2][0] + xw[3][0],
                      xw[0][1] + xw[1][1] + xw[2][1] + xw[3][1],
                      xw[0][2] + xw[1][2] + xw[2][2] + xw[3][2],
                      xw[0][3] + xw[1][3] + xw[2][3] + xw[3][3]);
      gbar(bar, 2 + k);
    }
  }
}

extern "C" void kernel_launch(void* const* d_in, const int* in_sizes, int n_in,
                              void* d_out, int out_size, void* d_ws, size_t ws_size,
                              hipStream_t stream) {
  const float* feat = (const float*)d_in[0];   // (2,256,512,512) f32
  const int*   mask = (const int*)d_in[1];     // (2,512,512) i32
  float* out = (float*)d_out;                  // (2,512,512) f32

  // ws layout (~1.1 MB; every byte read is written earlier this launch):
  char* ws = (char*)d_ws;
  uint8_t*  aA     = (uint8_t*)(ws);               // 524288
  uint8_t*  aB     = (uint8_t*)(ws + 524288);      // 524288
  float2*   mm     = (float2*)(ws + 1048576);      // 512*8  = 4096
  int4*     totals = (int4*)(ws + 1052672);        // 512*16 = 8192
  int4*     slots  = (int4*)(ws + 1060864);        // 5*512*16 = 40960
  unsigned* bar    = (unsigned*)(ws + 1101824);    // 6*4 = 24 (zeroed below)

  hipMemsetAsync(bar, 0, 64, stream);  // barrier counters (ws is poisoned)
  k_grabcut<<<NBLK, 256, 0, stream>>>(feat, mask, out, aA, aB, mm, totals,
                                      slots, bar);
}